// Round 2
// baseline (153.411 us; speedup 1.0000x reference)
//
#include <hip/hip_runtime.h>
#include <math.h>

#define DIM 16

// ---------------------------------------------------------------------------
// Precompute kernel: build C[4][81] coefficient tensors into d_ws.
//   A_i = Re(U^dag Z_i U)  (16x16, via f64 column evolution in LDS)
//   out_i(psi) = psi^T A_i psi = sum_{v in {0,1,2}^4} C_i[v] * prod_q g_{v_q}(t_q)
//   with per-qubit basis g = (1, cos t, sin t), t_q = tanh(p_q)*pi/2.
// Per-qubit pair map (m_q,k_q) -> basis coeffs:
//   (0,0): 0.5*g0 + 0.5*g1 ; (1,1): 0.5*g0 - 0.5*g1 ; (0,1),(1,0): 0.5*g2
// ---------------------------------------------------------------------------
__global__ __launch_bounds__(256) void quanv_precompute(const float* __restrict__ w,
                                                        float* __restrict__ C) {
  __shared__ double Ur[DIM][DIM];  // [col j][amplitude m]
  __shared__ double Ui[DIM][DIM];
  __shared__ double Ad[4][DIM][DIM];
  const int tid = threadIdx.x;

  if (tid < DIM) {
    const int j = tid;
    for (int m = 0; m < DIM; ++m) {
      Ur[j][m] = (m == j) ? 1.0 : 0.0;
      Ui[j][m] = 0.0;
    }
    for (int l = 0; l < 2; ++l) {
      for (int q = 0; q < 4; ++q) {
        double phi = (double)w[l * 12 + q * 3 + 0];
        double th  = (double)w[l * 12 + q * 3 + 1];
        double om  = (double)w[l * 12 + q * 3 + 2];
        double a  = 0.5 * (phi + om);
        double bb = 0.5 * (phi - om);
        double ct = cos(0.5 * th), st = sin(0.5 * th);
        double g00r =  cos(a) * ct, g00i = -sin(a) * ct;
        double g01r = -cos(bb) * st, g01i = -sin(bb) * st;
        double g10r =  cos(bb) * st, g10i = -sin(bb) * st;
        double g11r =  cos(a) * ct, g11i =  sin(a) * ct;
        const int bit = 1 << (3 - q);
        for (int m = 0; m < DIM; ++m) {
          if (m & bit) continue;
          const int m1 = m | bit;
          double v0r = Ur[j][m],  v0i = Ui[j][m];
          double v1r = Ur[j][m1], v1i = Ui[j][m1];
          Ur[j][m]  = g00r * v0r - g00i * v0i + g01r * v1r - g01i * v1i;
          Ui[j][m]  = g00r * v0i + g00i * v0r + g01r * v1i + g01i * v1r;
          Ur[j][m1] = g10r * v0r - g10i * v0i + g11r * v1r - g11i * v1i;
          Ui[j][m1] = g10r * v0i + g10i * v0r + g11r * v1i + g11i * v1r;
        }
      }
      const int r = (l % 3) + 1;
      for (int q = 0; q < 4; ++q) {
        const int c = q, t = (q + r) & 3;
        const int cbit = 1 << (3 - c), tbit = 1 << (3 - t);
        for (int m = 0; m < DIM; ++m) {
          if ((m & cbit) && !(m & tbit)) {
            const int m1 = m | tbit;
            double tr = Ur[j][m]; Ur[j][m] = Ur[j][m1]; Ur[j][m1] = tr;
            double ti = Ui[j][m]; Ui[j][m] = Ui[j][m1]; Ui[j][m1] = ti;
          }
        }
      }
    }
  }
  __syncthreads();

  // A_i[j][k] = sum_m sign_i(m) * (Ur[j][m]*Ur[k][m] + Ui[j][m]*Ui[k][m])
  for (int idx = tid; idx < 4 * DIM * DIM; idx += 256) {
    const int i = idx >> 8;
    const int j = (idx >> 4) & 15;
    const int k = idx & 15;
    double s = 0.0;
    for (int m = 0; m < DIM; ++m) {
      double term = Ur[j][m] * Ur[k][m] + Ui[j][m] * Ui[k][m];
      s += ((m >> (3 - i)) & 1) ? -term : term;
    }
    Ad[i][j][k] = s;
  }
  __syncthreads();

  // Contract A -> C[4][81].  Pair index p_q = 2*m_q + k_q.
  const double M[3][4] = {{0.5, 0.0, 0.0, 0.5},
                          {0.5, 0.0, 0.0, -0.5},
                          {0.0, 0.5, 0.5, 0.0}};
  for (int idx = tid; idx < 4 * 81; idx += 256) {
    const int i = idx / 81;
    const int rr = idx - i * 81;
    const int v0 = rr / 27, v1 = (rr / 9) % 3, v2 = (rr / 3) % 3, v3 = rr % 3;
    double s = 0.0;
    for (int p = 0; p < 256; ++p) {
      const int p0 = (p >> 6) & 3, p1 = (p >> 4) & 3, p2 = (p >> 2) & 3, p3 = p & 3;
      double f = M[v0][p0] * M[v1][p1] * M[v2][p2] * M[v3][p3];
      if (f != 0.0) {
        const int m = ((p0 >> 1) << 3) | ((p1 >> 1) << 2) | ((p2 >> 1) << 1) | (p3 >> 1);
        const int k = ((p0 & 1) << 3) | ((p1 & 1) << 2) | ((p2 & 1) << 1) | (p3 & 1);
        s += f * Ad[i][m][k];
      }
    }
    C[idx] = (float)s;
  }
}

// ---------------------------------------------------------------------------
// Main kernel: one thread per 2x2 patch.
//   t_q = tanh(p_q)*pi/2 via branch-free (u-1)/(u+1), u = e^{2x}
//   out_i = multilinear form in (1, cos t_q, sin t_q), 320 FMA.
// C reads are wave-uniform with compile-time offsets -> scalar loads.
// ---------------------------------------------------------------------------
static __device__ __forceinline__ void pix_trig(float xx, float& c, float& s) {
  xx = fminf(10.0f, fmaxf(-10.0f, xx));            // v_med3
  const float u = __expf(xx + xx);                 // v_exp (constants fold)
  const float th = (u - 1.0f) * __builtin_amdgcn_rcpf(u + 1.0f);
  __sincosf(th * 1.57079632679489662f, &s, &c);    // hw v_sin/v_cos, arg folds
}

__global__ __launch_bounds__(256) void quanv_main(const float* __restrict__ x,
                                                  const float* __restrict__ C,
                                                  float* __restrict__ out) {
  const int idx = blockIdx.x * 256 + threadIdx.x;   // 802816 threads exactly
  const int b   = idx / 12544;                      // 112*112
  const int rem = idx - b * 12544;
  const int i   = rem / 112;
  const int j   = rem - i * 112;

  const float* px = x + (size_t)b * 50176 + (size_t)(2 * i) * 224 + 2 * j;
  const float2 r0 = *(const float2*)(px);
  const float2 r1 = *(const float2*)(px + 224);

  float c0, s0, c1, s1, c2, s2, c3, s3;
  pix_trig(r0.x, c0, s0);
  pix_trig(r0.y, c1, s1);
  pix_trig(r1.x, c2, s2);
  pix_trig(r1.y, c3, s3);

  const float g0v[3] = {1.0f, c0, s0};
  const float g1v[3] = {1.0f, c1, s1};
  const float g2v[3] = {1.0f, c2, s2};

  float o[4];
#pragma unroll
  for (int oi = 0; oi < 4; ++oi) {
    const float* D = C + oi * 81;
    float acc0 = 0.0f;
#pragma unroll
    for (int v0 = 0; v0 < 3; ++v0) {
      float acc1 = 0.0f;
#pragma unroll
      for (int v1 = 0; v1 < 3; ++v1) {
        float acc2 = 0.0f;
#pragma unroll
        for (int v2 = 0; v2 < 3; ++v2) {
          const int base = ((v0 * 3 + v1) * 3 + v2) * 3;
          float t = fmaf(s3, D[base + 2], fmaf(c3, D[base + 1], D[base + 0]));
          acc2 = (v2 == 0) ? t : fmaf(g2v[v2], t, acc2);
        }
        acc1 = (v1 == 0) ? acc2 : fmaf(g1v[v1], acc2, acc1);
      }
      acc0 = (v0 == 0) ? acc1 : fmaf(g0v[v0], acc1, acc0);
    }
    o[oi] = acc0;
  }

  float* po = out + (size_t)b * 4 * 12544 + (size_t)i * 112 + j;
  po[0 * 12544] = o[0];
  po[1 * 12544] = o[1];
  po[2 * 12544] = o[2];
  po[3 * 12544] = o[3];
}

extern "C" void kernel_launch(void* const* d_in, const int* in_sizes, int n_in,
                              void* d_out, int out_size, void* d_ws, size_t ws_size,
                              hipStream_t stream) {
  const float* x = (const float*)d_in[0];   // (64,1,224,224) f32
  const float* w = (const float*)d_in[1];   // (2,4,3) f32
  float* out = (float*)d_out;               // (64,4,112,112) f32
  float* C   = (float*)d_ws;                // 4*81 floats = 1296 B

  quanv_precompute<<<1, 256, 0, stream>>>(w, C);
  quanv_main<<<3136, 256, 0, stream>>>(x, C, out);
}

// Round 5
// 42.832 us; speedup vs baseline: 3.5817x; 3.5817x over previous
//
#include <hip/hip_runtime.h>
#include <math.h>

#define DIM 16

// ---------------------------------------------------------------------------
// Precompute kernel: build C[4][81] coefficient tensors into d_ws.
//   A_i = Re(U^dag Z_i U)  (16x16, via f64 column evolution in LDS)
//   out_i(psi) = psi^T A_i psi = sum_{v in {0,1,2}^4} C_i[v] * prod_q g_{v_q}(t_q)
//   with per-qubit basis g = (1, cos t, sin t), t_q = tanh(p_q)*pi/2.
// Per-qubit pair map (m_q,k_q) -> basis v coefficients (only 2 nonzeros each):
//   v=0: (0,0)+.5, (1,1)+.5 ; v=1: (0,0)+.5, (1,1)-.5 ; v=2: (0,1)+.5, (1,0)+.5
// i.e. choosing bit b for a qubit with basis v: m=b, k=(v==2)?b^1:b,
// weight 0.5, sign flips iff (v==1 && b==1).
// ---------------------------------------------------------------------------
__global__ __launch_bounds__(256) void quanv_precompute(const float* __restrict__ w,
                                                        float* __restrict__ C) {
  __shared__ double Ur[DIM][DIM];  // [col j][amplitude m]
  __shared__ double Ui[DIM][DIM];
  __shared__ double Ad[4][DIM][DIM];
  const int tid = threadIdx.x;

  if (tid < DIM) {
    const int j = tid;
    for (int m = 0; m < DIM; ++m) {
      Ur[j][m] = (m == j) ? 1.0 : 0.0;
      Ui[j][m] = 0.0;
    }
    for (int l = 0; l < 2; ++l) {
      for (int q = 0; q < 4; ++q) {
        double phi = (double)w[l * 12 + q * 3 + 0];
        double th  = (double)w[l * 12 + q * 3 + 1];
        double om  = (double)w[l * 12 + q * 3 + 2];
        double a  = 0.5 * (phi + om);
        double bb = 0.5 * (phi - om);
        double ct = cos(0.5 * th), st = sin(0.5 * th);
        double g00r =  cos(a) * ct, g00i = -sin(a) * ct;
        double g01r = -cos(bb) * st, g01i = -sin(bb) * st;
        double g10r =  cos(bb) * st, g10i = -sin(bb) * st;
        double g11r =  cos(a) * ct, g11i =  sin(a) * ct;
        const int bit = 1 << (3 - q);
        for (int m = 0; m < DIM; ++m) {
          if (m & bit) continue;
          const int m1 = m | bit;
          double v0r = Ur[j][m],  v0i = Ui[j][m];
          double v1r = Ur[j][m1], v1i = Ui[j][m1];
          Ur[j][m]  = g00r * v0r - g00i * v0i + g01r * v1r - g01i * v1i;
          Ui[j][m]  = g00r * v0i + g00i * v0r + g01r * v1i + g01i * v1r;
          Ur[j][m1] = g10r * v0r - g10i * v0i + g11r * v1r - g11i * v1i;
          Ui[j][m1] = g10r * v0i + g10i * v0r + g11r * v1i + g11i * v1r;
        }
      }
      const int r = (l % 3) + 1;
      for (int q = 0; q < 4; ++q) {
        const int c = q, t = (q + r) & 3;
        const int cbit = 1 << (3 - c), tbit = 1 << (3 - t);
        for (int m = 0; m < DIM; ++m) {
          if ((m & cbit) && !(m & tbit)) {
            const int m1 = m | tbit;
            double tr = Ur[j][m]; Ur[j][m] = Ur[j][m1]; Ur[j][m1] = tr;
            double ti = Ui[j][m]; Ui[j][m] = Ui[j][m1]; Ui[j][m1] = ti;
          }
        }
      }
    }
  }
  __syncthreads();

  // A_i[j][k] = sum_m sign_i(m) * (Ur[j][m]*Ur[k][m] + Ui[j][m]*Ui[k][m])
  for (int idx = tid; idx < 4 * DIM * DIM; idx += 256) {
    const int i = idx >> 8;
    const int j = (idx >> 4) & 15;
    const int k = idx & 15;
    double s = 0.0;
    for (int m = 0; m < DIM; ++m) {
      double term = Ur[j][m] * Ur[k][m] + Ui[j][m] * Ui[k][m];
      s += ((m >> (3 - i)) & 1) ? -term : term;
    }
    Ad[i][j][k] = s;
  }
  __syncthreads();

  // Contract A -> C[4][81]: 16-term signed sum, pure bit arithmetic (no local
  // arrays -> no scratch).
  for (int idx = tid; idx < 4 * 81; idx += 256) {
    const int i = idx / 81;
    const int rr = idx - i * 81;
    const int v0 = rr / 27, v1 = (rr / 9) % 3, v2 = (rr / 3) % 3, v3 = rr % 3;
    double s = 0.0;
#pragma unroll
    for (int b = 0; b < 16; ++b) {
      const int b0 = (b >> 3) & 1, b1 = (b >> 2) & 1, b2 = (b >> 1) & 1, b3 = b & 1;
      const int k0 = (v0 == 2) ? (b0 ^ 1) : b0;
      const int k1 = (v1 == 2) ? (b1 ^ 1) : b1;
      const int k2 = (v2 == 2) ? (b2 ^ 1) : b2;
      const int k3 = (v3 == 2) ? (b3 ^ 1) : b3;
      const int neg = (((v0 == 1) & b0) ^ ((v1 == 1) & b1) ^
                       ((v2 == 1) & b2) ^ ((v3 == 1) & b3));
      const int k = (k0 << 3) | (k1 << 2) | (k2 << 1) | k3;
      const double term = Ad[i][b][k];   // b == m index
      s += neg ? -term : term;
    }
    C[idx] = (float)(0.0625 * s);
  }
}

// ---------------------------------------------------------------------------
// Main kernel: one thread per 2x2 patch.
//   t_q = tanh(p_q)*pi/2 via branch-free (u-1)/(u+1), u = e^{2x}
//   out_i = multilinear form in (1, cos t_q, sin t_q), 320 FMA.
// C reads are wave-uniform with compile-time offsets -> scalar loads.
// ---------------------------------------------------------------------------
static __device__ __forceinline__ void pix_trig(float xx, float& c, float& s) {
  xx = fminf(10.0f, fmaxf(-10.0f, xx));            // v_med3
  const float u = __expf(xx + xx);                 // v_exp (constants fold)
  const float th = (u - 1.0f) * __builtin_amdgcn_rcpf(u + 1.0f);
  __sincosf(th * 1.57079632679489662f, &s, &c);    // hw v_sin/v_cos, arg folds
}

__global__ __launch_bounds__(256) void quanv_main(const float* __restrict__ x,
                                                  const float* __restrict__ C,
                                                  float* __restrict__ out) {
  const int idx = blockIdx.x * 256 + threadIdx.x;   // 802816 threads exactly
  const int b   = idx / 12544;                      // 112*112
  const int rem = idx - b * 12544;
  const int i   = rem / 112;
  const int j   = rem - i * 112;

  const float* px = x + (size_t)b * 50176 + (size_t)(2 * i) * 224 + 2 * j;
  const float2 r0 = *(const float2*)(px);
  const float2 r1 = *(const float2*)(px + 224);

  float c0, s0, c1, s1, c2, s2, c3, s3;
  pix_trig(r0.x, c0, s0);
  pix_trig(r0.y, c1, s1);
  pix_trig(r1.x, c2, s2);
  pix_trig(r1.y, c3, s3);

  const float g0v[3] = {1.0f, c0, s0};
  const float g1v[3] = {1.0f, c1, s1};
  const float g2v[3] = {1.0f, c2, s2};

  float o[4];
#pragma unroll
  for (int oi = 0; oi < 4; ++oi) {
    const float* D = C + oi * 81;
    float acc0 = 0.0f;
#pragma unroll
    for (int v0 = 0; v0 < 3; ++v0) {
      float acc1 = 0.0f;
#pragma unroll
      for (int v1 = 0; v1 < 3; ++v1) {
        float acc2 = 0.0f;
#pragma unroll
        for (int v2 = 0; v2 < 3; ++v2) {
          const int base = ((v0 * 3 + v1) * 3 + v2) * 3;
          float t = fmaf(s3, D[base + 2], fmaf(c3, D[base + 1], D[base + 0]));
          acc2 = (v2 == 0) ? t : fmaf(g2v[v2], t, acc2);
        }
        acc1 = (v1 == 0) ? acc2 : fmaf(g1v[v1], acc2, acc1);
      }
      acc0 = (v0 == 0) ? acc1 : fmaf(g0v[v0], acc1, acc0);
    }
    o[oi] = acc0;
  }

  float* po = out + (size_t)b * 4 * 12544 + (size_t)i * 112 + j;
  po[0 * 12544] = o[0];
  po[1 * 12544] = o[1];
  po[2 * 12544] = o[2];
  po[3 * 12544] = o[3];
}

extern "C" void kernel_launch(void* const* d_in, const int* in_sizes, int n_in,
                              void* d_out, int out_size, void* d_ws, size_t ws_size,
                              hipStream_t stream) {
  const float* x = (const float*)d_in[0];   // (64,1,224,224) f32
  const float* w = (const float*)d_in[1];   // (2,4,3) f32
  float* out = (float*)d_out;               // (64,4,112,112) f32
  float* C   = (float*)d_ws;                // 4*81 floats = 1296 B

  quanv_precompute<<<1, 256, 0, stream>>>(w, C);
  quanv_main<<<3136, 256, 0, stream>>>(x, C, out);
}

// Round 8
// 25.002 us; speedup vs baseline: 6.1361x; 1.7132x over previous
//
#include <hip/hip_runtime.h>
#include <math.h>

#define DIM 16

// ---------------------------------------------------------------------------
// Precompute kernel (all f32 — the reference circuit is complex64 itself):
// build C[4][81] coefficient tensors into d_ws.
//   A_i = Re(U^dag Z_i U)  (16x16, column evolution in LDS)
//   out_i(psi) = psi^T A_i psi = sum_{v in {0,1,2}^4} C_i[v] * prod_q g_{v_q}(t_q)
//   with per-qubit basis g = (1, cos t, sin t), t_q = tanh(p_q)*pi/2.
// Phase 0: 8 threads compute the 8 Rot-gate 2x2 complex matrices (hw sincos).
// Phase 1: 16 threads evolve the 16 unitary columns (f32 butterflies, CNOT swaps).
// Phase 2: A_i[j][k] build.  Phase 3: sparse contraction A -> C (16-term sums).
// ---------------------------------------------------------------------------
__global__ __launch_bounds__(256) void quanv_precompute(const float* __restrict__ w,
                                                        float* __restrict__ C) {
  __shared__ float G[8][8];            // per gate: 00r,00i,01r,01i,10r,10i,11r,11i
  __shared__ float Ur[DIM][DIM + 1];   // [col j][amplitude m], padded
  __shared__ float Ui[DIM][DIM + 1];
  __shared__ float Ad[4][DIM][DIM];
  const int tid = threadIdx.x;

  if (tid < 8) {
    const int l = tid >> 2, q = tid & 3;
    const float phi = w[l * 12 + q * 3 + 0];
    const float th  = w[l * 12 + q * 3 + 1];
    const float om  = w[l * 12 + q * 3 + 2];
    const float a  = 0.5f * (phi + om);
    const float bb = 0.5f * (phi - om);
    float ct, st, ca, sa, cb, sb;
    __sincosf(0.5f * th, &st, &ct);
    __sincosf(a, &sa, &ca);
    __sincosf(bb, &sb, &cb);
    G[tid][0] =  ca * ct; G[tid][1] = -sa * ct;   // g00 = e^{-ia} ct
    G[tid][2] = -cb * st; G[tid][3] = -sb * st;   // g01 = -e^{+ib} st
    G[tid][4] =  cb * st; G[tid][5] = -sb * st;   // g10 = e^{-ib} st
    G[tid][6] =  ca * ct; G[tid][7] =  sa * ct;   // g11 = e^{+ia} ct
  }
  __syncthreads();

  if (tid < DIM) {
    const int j = tid;
    for (int m = 0; m < DIM; ++m) {
      Ur[j][m] = (m == j) ? 1.0f : 0.0f;
      Ui[j][m] = 0.0f;
    }
    for (int l = 0; l < 2; ++l) {
      for (int q = 0; q < 4; ++q) {
        const int gi = l * 4 + q;
        const float g00r = G[gi][0], g00i = G[gi][1];
        const float g01r = G[gi][2], g01i = G[gi][3];
        const float g10r = G[gi][4], g10i = G[gi][5];
        const float g11r = G[gi][6], g11i = G[gi][7];
        const int bit = 1 << (3 - q);
        for (int m = 0; m < DIM; ++m) {
          if (m & bit) continue;
          const int m1 = m | bit;
          const float v0r = Ur[j][m],  v0i = Ui[j][m];
          const float v1r = Ur[j][m1], v1i = Ui[j][m1];
          Ur[j][m]  = g00r * v0r - g00i * v0i + g01r * v1r - g01i * v1i;
          Ui[j][m]  = g00r * v0i + g00i * v0r + g01r * v1i + g01i * v1r;
          Ur[j][m1] = g10r * v0r - g10i * v0i + g11r * v1r - g11i * v1i;
          Ui[j][m1] = g10r * v0i + g10i * v0r + g11r * v1i + g11i * v1r;
        }
      }
      const int r = (l % 3) + 1;
      for (int q = 0; q < 4; ++q) {
        const int c = q, t = (q + r) & 3;
        const int cbit = 1 << (3 - c), tbit = 1 << (3 - t);
        for (int m = 0; m < DIM; ++m) {
          if ((m & cbit) && !(m & tbit)) {
            const int m1 = m | tbit;
            float tr = Ur[j][m]; Ur[j][m] = Ur[j][m1]; Ur[j][m1] = tr;
            float ti = Ui[j][m]; Ui[j][m] = Ui[j][m1]; Ui[j][m1] = ti;
          }
        }
      }
    }
  }
  __syncthreads();

  // A_i[j][k] = sum_m sign_i(m) * (Ur[j][m]*Ur[k][m] + Ui[j][m]*Ui[k][m])
  for (int idx = tid; idx < 4 * DIM * DIM; idx += 256) {
    const int i = idx >> 8;
    const int j = (idx >> 4) & 15;
    const int k = idx & 15;
    float s = 0.0f;
    for (int m = 0; m < DIM; ++m) {
      const float term = Ur[j][m] * Ur[k][m] + Ui[j][m] * Ui[k][m];
      s += ((m >> (3 - i)) & 1) ? -term : term;
    }
    Ad[i][j][k] = s;
  }
  __syncthreads();

  // Contract A -> C[4][81]: 16-term signed sum, pure bit arithmetic.
  // Per-qubit pair map (only 2 nonzeros per basis v): choosing bit b for a
  // qubit with basis v: m=b, k=(v==2)?b^1:b, weight 0.5, sign flips iff
  // (v==1 && b==1).
  for (int idx = tid; idx < 4 * 81; idx += 256) {
    const int i = idx / 81;
    const int rr = idx - i * 81;
    const int v0 = rr / 27, v1 = (rr / 9) % 3, v2 = (rr / 3) % 3, v3 = rr % 3;
    float s = 0.0f;
#pragma unroll
    for (int b = 0; b < 16; ++b) {
      const int b0 = (b >> 3) & 1, b1 = (b >> 2) & 1, b2 = (b >> 1) & 1, b3 = b & 1;
      const int k0 = (v0 == 2) ? (b0 ^ 1) : b0;
      const int k1 = (v1 == 2) ? (b1 ^ 1) : b1;
      const int k2 = (v2 == 2) ? (b2 ^ 1) : b2;
      const int k3 = (v3 == 2) ? (b3 ^ 1) : b3;
      const int neg = (((v0 == 1) & b0) ^ ((v1 == 1) & b1) ^
                       ((v2 == 1) & b2) ^ ((v3 == 1) & b3));
      const int k = (k0 << 3) | (k1 << 2) | (k2 << 1) | k3;
      const float term = Ad[i][b][k];   // b == m index
      s += neg ? -term : term;
    }
    C[idx] = 0.0625f * s;
  }
}

// ---------------------------------------------------------------------------
// Main kernel: one thread per 2x2 patch.
//   t_q = tanh(p_q)*pi/2 via branch-free (u-1)/(u+1), u = e^{2x}
//   out_i = multilinear form in (1, cos t_q, sin t_q), 320 FMA.
// C reads are wave-uniform with compile-time offsets -> scalar loads.
// ---------------------------------------------------------------------------
static __device__ __forceinline__ void pix_trig(float xx, float& c, float& s) {
  xx = fminf(10.0f, fmaxf(-10.0f, xx));            // v_med3
  const float u = __expf(xx + xx);                 // v_exp (constants fold)
  const float th = (u - 1.0f) * __builtin_amdgcn_rcpf(u + 1.0f);
  __sincosf(th * 1.57079632679489662f, &s, &c);    // hw v_sin/v_cos, arg folds
}

__global__ __launch_bounds__(256) void quanv_main(const float* __restrict__ x,
                                                  const float* __restrict__ C,
                                                  float* __restrict__ out) {
  const int idx = blockIdx.x * 256 + threadIdx.x;   // 802816 threads exactly
  const int b   = idx / 12544;                      // 112*112
  const int rem = idx - b * 12544;
  const int i   = rem / 112;
  const int j   = rem - i * 112;

  const float* px = x + (size_t)b * 50176 + (size_t)(2 * i) * 224 + 2 * j;
  const float2 r0 = *(const float2*)(px);
  const float2 r1 = *(const float2*)(px + 224);

  float c0, s0, c1, s1, c2, s2, c3, s3;
  pix_trig(r0.x, c0, s0);
  pix_trig(r0.y, c1, s1);
  pix_trig(r1.x, c2, s2);
  pix_trig(r1.y, c3, s3);

  const float g0v[3] = {1.0f, c0, s0};
  const float g1v[3] = {1.0f, c1, s1};
  const float g2v[3] = {1.0f, c2, s2};

  float o[4];
#pragma unroll
  for (int oi = 0; oi < 4; ++oi) {
    const float* D = C + oi * 81;
    float acc0 = 0.0f;
#pragma unroll
    for (int v0 = 0; v0 < 3; ++v0) {
      float acc1 = 0.0f;
#pragma unroll
      for (int v1 = 0; v1 < 3; ++v1) {
        float acc2 = 0.0f;
#pragma unroll
        for (int v2 = 0; v2 < 3; ++v2) {
          const int base = ((v0 * 3 + v1) * 3 + v2) * 3;
          float t = fmaf(s3, D[base + 2], fmaf(c3, D[base + 1], D[base + 0]));
          acc2 = (v2 == 0) ? t : fmaf(g2v[v2], t, acc2);
        }
        acc1 = (v1 == 0) ? acc2 : fmaf(g1v[v1], acc2, acc1);
      }
      acc0 = (v0 == 0) ? acc1 : fmaf(g0v[v0], acc1, acc0);
    }
    o[oi] = acc0;
  }

  float* po = out + (size_t)b * 4 * 12544 + (size_t)i * 112 + j;
  po[0 * 12544] = o[0];
  po[1 * 12544] = o[1];
  po[2 * 12544] = o[2];
  po[3 * 12544] = o[3];
}

extern "C" void kernel_launch(void* const* d_in, const int* in_sizes, int n_in,
                              void* d_out, int out_size, void* d_ws, size_t ws_size,
                              hipStream_t stream) {
  const float* x = (const float*)d_in[0];   // (64,1,224,224) f32
  const float* w = (const float*)d_in[1];   // (2,4,3) f32
  float* out = (float*)d_out;               // (64,4,112,112) f32
  float* C   = (float*)d_ws;                // 4*81 floats = 1296 B

  quanv_precompute<<<1, 256, 0, stream>>>(w, C);
  quanv_main<<<3136, 256, 0, stream>>>(x, C, out);
}

// Round 10
// 23.657 us; speedup vs baseline: 6.4847x; 1.0568x over previous
//
#include <hip/hip_runtime.h>
#include <math.h>

#define DIM 16

// ---------------------------------------------------------------------------
// Precompute kernel: build C[4][81] coefficient tensors into d_ws.
//   A_i = Re(U^dag Z_i U); out_i(psi) = sum_{v in 3^4} C_i[v] prod_q g_{v_q}(t_q),
//   g = (1, cos t, sin t).
// Phase 1: thread j (j<16) evolves unitary column j ENTIRELY IN REGISTERS
//   (fully unrolled butterflies; CNOT swaps are register renames), then one
//   LDS write of U. No serial LDS round-trips.
// Phase 2: thread (j,k) computes the 16 shared products once -> 4 Ad entries.
// Phase 3: sparse contraction Ad -> C (16 independent LDS reads, unrolled).
// ---------------------------------------------------------------------------
__global__ __launch_bounds__(256) void quanv_precompute(const float* __restrict__ w,
                                                        float* __restrict__ C) {
  __shared__ float Ur[DIM][20];        // padded, 16B-aligned rows
  __shared__ float Ui[DIM][20];
  __shared__ float Ad[4][DIM][DIM];
  const int tid = threadIdx.x;

  if (tid < DIM) {
    float ur[DIM], ui[DIM];
#pragma unroll
    for (int m = 0; m < DIM; ++m) { ur[m] = (m == tid) ? 1.0f : 0.0f; ui[m] = 0.0f; }
#pragma unroll
    for (int l = 0; l < 2; ++l) {
#pragma unroll
      for (int q = 0; q < 4; ++q) {
        const float phi = w[l * 12 + q * 3 + 0];
        const float th  = w[l * 12 + q * 3 + 1];
        const float om  = w[l * 12 + q * 3 + 2];
        const float a  = 0.5f * (phi + om);
        const float bb = 0.5f * (phi - om);
        float ct, st, ca, sa, cb, sb;
        __sincosf(0.5f * th, &st, &ct);
        __sincosf(a, &sa, &ca);
        __sincosf(bb, &sb, &cb);
        const float g00r =  ca * ct, g00i = -sa * ct;   // e^{-ia} ct
        const float g01r = -cb * st, g01i = -sb * st;   // -e^{+ib} st
        const float g10r =  cb * st, g10i = -sb * st;   // e^{-ib} st
        const float g11r =  ca * ct, g11i =  sa * ct;   // e^{+ia} ct
        const int bit = 1 << (3 - q);
#pragma unroll
        for (int m = 0; m < DIM; ++m) {
          if (m & bit) continue;
          const int m1 = m | bit;
          const float v0r = ur[m],  v0i = ui[m];
          const float v1r = ur[m1], v1i = ui[m1];
          ur[m]  = g00r * v0r - g00i * v0i + g01r * v1r - g01i * v1i;
          ui[m]  = g00r * v0i + g00i * v0r + g01r * v1i + g01i * v1r;
          ur[m1] = g10r * v0r - g10i * v0i + g11r * v1r - g11i * v1i;
          ui[m1] = g10r * v0i + g10i * v0r + g11r * v1i + g11i * v1r;
        }
      }
      const int r = (l % 3) + 1;     // compile-time after unroll
#pragma unroll
      for (int q = 0; q < 4; ++q) {
        const int cbit = 1 << (3 - q);
        const int tbit = 1 << (3 - ((q + r) & 3));
#pragma unroll
        for (int m = 0; m < DIM; ++m) {
          if ((m & cbit) && !(m & tbit)) {
            const int m1 = m | tbit;
            float t;
            t = ur[m]; ur[m] = ur[m1]; ur[m1] = t;
            t = ui[m]; ui[m] = ui[m1]; ui[m1] = t;
          }
        }
      }
    }
#pragma unroll
    for (int m = 0; m < DIM; ++m) { Ur[tid][m] = ur[m]; Ui[tid][m] = ui[m]; }
  }
  __syncthreads();

  // Phase 2: tid -> (j,k). 16 shared products -> 4 signed sums.
  {
    const int j = tid >> 4, k = tid & 15;
    float term[DIM];
#pragma unroll
    for (int m = 0; m < DIM; ++m)
      term[m] = Ur[j][m] * Ur[k][m] + Ui[j][m] * Ui[k][m];
#pragma unroll
    for (int i = 0; i < 4; ++i) {
      float s = 0.0f;
#pragma unroll
      for (int m = 0; m < DIM; ++m)
        s += ((m >> (3 - i)) & 1) ? -term[m] : term[m];
      Ad[i][j][k] = s;
    }
  }
  __syncthreads();

  // Phase 3: contract Ad -> C[4][81]. Choosing bit b for a qubit with basis v:
  // m=b, k=(v==2)?b^1:b, weight 0.5, sign flips iff (v==1 && b==1).
  for (int idx = tid; idx < 4 * 81; idx += 256) {
    const int i = idx / 81;
    const int rr = idx - i * 81;
    const int v0 = rr / 27, v1 = (rr / 9) % 3, v2 = (rr / 3) % 3, v3 = rr % 3;
    float s = 0.0f;
#pragma unroll
    for (int b = 0; b < 16; ++b) {
      const int b0 = (b >> 3) & 1, b1 = (b >> 2) & 1, b2 = (b >> 1) & 1, b3 = b & 1;
      const int k0 = (v0 == 2) ? (b0 ^ 1) : b0;
      const int k1 = (v1 == 2) ? (b1 ^ 1) : b1;
      const int k2 = (v2 == 2) ? (b2 ^ 1) : b2;
      const int k3 = (v3 == 2) ? (b3 ^ 1) : b3;
      const int neg = (((v0 == 1) & b0) ^ ((v1 == 1) & b1) ^
                       ((v2 == 1) & b2) ^ ((v3 == 1) & b3));
      const int k = (k0 << 3) | (k1 << 2) | (k2 << 1) | k3;
      const float term = Ad[i][b][k];
      s += neg ? -term : term;
    }
    C[idx] = 0.0625f * s;
  }
}

// ---------------------------------------------------------------------------
// Main kernel (unchanged from R8): one thread per 2x2 patch.
//   t_q = tanh(p_q)*pi/2 via branch-free (u-1)/(u+1), u = e^{2x}
//   out_i = multilinear form in (1, cos t_q, sin t_q), 320 FMA.
// C reads are wave-uniform with compile-time offsets -> scalar loads.
// ---------------------------------------------------------------------------
static __device__ __forceinline__ void pix_trig(float xx, float& c, float& s) {
  xx = fminf(10.0f, fmaxf(-10.0f, xx));            // v_med3
  const float u = __expf(xx + xx);                 // v_exp (constants fold)
  const float th = (u - 1.0f) * __builtin_amdgcn_rcpf(u + 1.0f);
  __sincosf(th * 1.57079632679489662f, &s, &c);    // hw v_sin/v_cos, arg folds
}

__global__ __launch_bounds__(256) void quanv_main(const float* __restrict__ x,
                                                  const float* __restrict__ C,
                                                  float* __restrict__ out) {
  const int idx = blockIdx.x * 256 + threadIdx.x;   // 802816 threads exactly
  const int b   = idx / 12544;                      // 112*112
  const int rem = idx - b * 12544;
  const int i   = rem / 112;
  const int j   = rem - i * 112;

  const float* px = x + (size_t)b * 50176 + (size_t)(2 * i) * 224 + 2 * j;
  const float2 r0 = *(const float2*)(px);
  const float2 r1 = *(const float2*)(px + 224);

  float c0, s0, c1, s1, c2, s2, c3, s3;
  pix_trig(r0.x, c0, s0);
  pix_trig(r0.y, c1, s1);
  pix_trig(r1.x, c2, s2);
  pix_trig(r1.y, c3, s3);

  const float g0v[3] = {1.0f, c0, s0};
  const float g1v[3] = {1.0f, c1, s1};
  const float g2v[3] = {1.0f, c2, s2};

  float o[4];
#pragma unroll
  for (int oi = 0; oi < 4; ++oi) {
    const float* D = C + oi * 81;
    float acc0 = 0.0f;
#pragma unroll
    for (int v0 = 0; v0 < 3; ++v0) {
      float acc1 = 0.0f;
#pragma unroll
      for (int v1 = 0; v1 < 3; ++v1) {
        float acc2 = 0.0f;
#pragma unroll
        for (int v2 = 0; v2 < 3; ++v2) {
          const int base = ((v0 * 3 + v1) * 3 + v2) * 3;
          float t = fmaf(s3, D[base + 2], fmaf(c3, D[base + 1], D[base + 0]));
          acc2 = (v2 == 0) ? t : fmaf(g2v[v2], t, acc2);
        }
        acc1 = (v1 == 0) ? acc2 : fmaf(g1v[v1], acc2, acc1);
      }
      acc0 = (v0 == 0) ? acc1 : fmaf(g0v[v0], acc1, acc0);
    }
    o[oi] = acc0;
  }

  float* po = out + (size_t)b * 4 * 12544 + (size_t)i * 112 + j;
  po[0 * 12544] = o[0];
  po[1 * 12544] = o[1];
  po[2 * 12544] = o[2];
  po[3 * 12544] = o[3];
}

extern "C" void kernel_launch(void* const* d_in, const int* in_sizes, int n_in,
                              void* d_out, int out_size, void* d_ws, size_t ws_size,
                              hipStream_t stream) {
  const float* x = (const float*)d_in[0];   // (64,1,224,224) f32
  const float* w = (const float*)d_in[1];   // (2,4,3) f32
  float* out = (float*)d_out;               // (64,4,112,112) f32
  float* C   = (float*)d_ws;                // 4*81 floats = 1296 B

  quanv_precompute<<<1, 256, 0, stream>>>(w, C);
  quanv_main<<<3136, 256, 0, stream>>>(x, C, out);
}